// Round 7
// baseline (345.795 us; speedup 1.0000x reference)
//
#include <hip/hip_runtime.h>

typedef __attribute__((ext_vector_type(8))) short short8;
typedef __attribute__((ext_vector_type(4))) short short4v;
typedef __attribute__((ext_vector_type(4))) float f32x4;
typedef __attribute__((ext_vector_type(4))) unsigned short us4;
typedef unsigned short ushort_t;
typedef unsigned int uint_t;

typedef const __attribute__((address_space(1))) void* gas1;
typedef __attribute__((address_space(3))) void* las3;

__device__ __forceinline__ ushort_t f2b(float f) {
  union { float f; uint_t u; } v; v.f = f;
  return (ushort_t)((v.u + 0x7fffu + ((v.u >> 16) & 1u)) >> 16);
}

__device__ __forceinline__ float b2f(ushort_t u) {
  union { uint_t u; float f; } v; v.u = ((uint_t)u) << 16;
  return v.f;
}

// pack 2 f32 -> 2 bf16 in one u32 (RNE) — T12 primitive
__device__ __forceinline__ uint_t cvtpk(float lo, float hi) {
  uint_t r;
  asm("v_cvt_pk_bf16_f32 %0, %1, %2" : "=v"(r) : "v"(lo), "v"(hi));
  return r;
}

__device__ __forceinline__ void gld_lds16(const ushort_t* g, void* l) {
  __builtin_amdgcn_global_load_lds((gas1)g, (las3)l, 16, 0, 0);
}

__device__ __forceinline__ float max3f(float a, float b, float c) {
  return fmaxf(fmaxf(a, b), c);   // clang fuses to v_max3_f32
}

// mfma 16x16x16 bf16 (K=16): A,B = 4 bf16/lane (2 VGPR), C/D = 4 f32
__device__ __forceinline__ f32x4 mfma16(short4v a, short4v b, f32x4 c) {
#if __has_builtin(__builtin_amdgcn_mfma_f32_16x16x16bf16_1k)
  return __builtin_amdgcn_mfma_f32_16x16x16bf16_1k(a, b, c, 0, 0, 0);
#else
  f32x4 d = c;
  asm volatile("v_mfma_f32_16x16x16_bf16 %0, %1, %2, %0\n\ts_nop 4"
               : "+v"(d) : "v"(a), "v"(b));
  return d;
#endif
}

// ---------------- convert x: f32 -> bf16, 4 elems/thread ----------------
__global__ void cvt_x_kernel(const float* __restrict__ x, ushort_t* __restrict__ xb, int n4) {
  int i = blockIdx.x * blockDim.x + threadIdx.x;
  if (i >= n4) return;
  float4 v = ((const float4*)x)[i];
  ushort4 o;
  o.x = f2b(v.x); o.y = f2b(v.y); o.z = f2b(v.z); o.w = f2b(v.w);
  ((ushort4*)xb)[i] = o;
}

// ------- convert + transpose W [512][512] f32 -> WT bf16, LDS-tiled -------
__global__ void cvt_wt_kernel(const float* __restrict__ W0, const float* __restrict__ W1,
                              const float* __restrict__ W2, const float* __restrict__ W3,
                              ushort_t* __restrict__ T0, ushort_t* __restrict__ T1,
                              ushort_t* __restrict__ T2, ushort_t* __restrict__ T3) {
  const float* W; ushort_t* T;
  switch (blockIdx.z) {
    case 0: W = W0; T = T0; break;
    case 1: W = W1; T = T1; break;
    case 2: W = W2; T = T2; break;
    default: W = W3; T = T3; break;
  }
  __shared__ ushort_t Tl[64 * 68];
  int t = threadIdx.x;
  int kt = blockIdx.x & 7, nt = blockIdx.x >> 3;
  int krow = t >> 4;
  int ncol = (t & 15) * 4;
#pragma unroll
  for (int j = 0; j < 4; ++j) {
    int k = j * 16 + krow;
    float4 v = *(const float4*)&W[(size_t)(kt * 64 + k) * 512 + nt * 64 + ncol];
    const float* vf = (const float*)&v;
#pragma unroll
    for (int e = 0; e < 4; ++e)
      Tl[(ncol + e) * 68 + k] = f2b(vf[e]);
  }
  __syncthreads();
#pragma unroll
  for (int j = 0; j < 4; ++j) {
    int f = j * 1024 + t * 4;
    int n = f >> 6, k = f & 63;
    *(ushort4*)&T[(size_t)(nt * 64 + n) * 512 + kt * 64 + k] =
        *(const ushort4*)&Tl[n * 68 + k];
  }
}

// ---------------- QKV projection GEMM, m97-style LDS-staged ----------------
__global__ __launch_bounds__(256) void gemm_qkv_kernel(
    const ushort_t* __restrict__ A,
    const ushort_t* __restrict__ WqT, const ushort_t* __restrict__ WkT,
    const ushort_t* __restrict__ WvT,
    ushort_t* __restrict__ Qo, ushort_t* __restrict__ Ko, ushort_t* __restrict__ VTo) {
  const int K = 512, N = 512, S = 4096;
  const ushort_t* BT; ushort_t* out; int mode;
  switch (blockIdx.z) {
    case 0: BT = WqT; out = Qo;  mode = 0; break;
    case 1: BT = WkT; out = Ko;  mode = 0; break;
    default: BT = WvT; out = VTo; mode = 1; break;
  }
  __shared__ ushort_t Al[128 * 64];
  __shared__ ushort_t Bl[128 * 64];

  int tid = threadIdx.x, lane = tid & 63, w = tid >> 6;
  int g = lane >> 4, ln = lane & 15;
  int wr = w >> 1, wc = w & 1;
  int m0 = blockIdx.y * 128;
  int n0 = blockIdx.x * 128;

  f32x4 acc[4][4];
  const f32x4 zz = {0.f, 0.f, 0.f, 0.f};
#pragma unroll
  for (int i = 0; i < 4; ++i)
#pragma unroll
    for (int j = 0; j < 4; ++j) acc[i][j] = zz;

  for (int kt = 0; kt < 8; ++kt) {
    __syncthreads();
#pragma unroll
    for (int i = 0; i < 4; ++i) {
      int p = i * 256 + tid, row = p >> 3, sl = p & 7, sp = sl ^ (row & 7);
      gld_lds16(A + (size_t)(m0 + row) * K + kt * 64 + sp * 8,
                (char*)Al + (i * 256 + (tid & 192)) * 16);
    }
#pragma unroll
    for (int i = 0; i < 4; ++i) {
      int p = i * 256 + tid, row = p >> 3, sl = p & 7, sp = sl ^ (row & 7);
      gld_lds16(BT + (size_t)(n0 + row) * K + kt * 64 + sp * 8,
                (char*)Bl + (i * 256 + (tid & 192)) * 16);
    }
    __syncthreads();

#pragma unroll
    for (int kc = 0; kc < 2; ++kc) {
      short8 af[4], bf[4];
#pragma unroll
      for (int mt = 0; mt < 4; ++mt) {
        int row = wr * 64 + mt * 16 + ln;
        af[mt] = *(const short8*)((char*)Al + row * 128 + (((kc * 4 + g) ^ (row & 7)) * 16));
      }
#pragma unroll
      for (int nt = 0; nt < 4; ++nt) {
        int row = wc * 64 + nt * 16 + ln;
        bf[nt] = *(const short8*)((char*)Bl + row * 128 + (((kc * 4 + g) ^ (row & 7)) * 16));
      }
#pragma unroll
      for (int mt = 0; mt < 4; ++mt)
#pragma unroll
        for (int nt = 0; nt < 4; ++nt)
          acc[mt][nt] = __builtin_amdgcn_mfma_f32_16x16x32_bf16(af[mt], bf[nt], acc[mt][nt], 0, 0, 0);
    }
  }

  if (mode == 0) {
#pragma unroll
    for (int mt = 0; mt < 4; ++mt)
#pragma unroll
      for (int nt = 0; nt < 4; ++nt)
#pragma unroll
        for (int jj = 0; jj < 4; ++jj) {
          int m = m0 + wr * 64 + mt * 16 + 4 * g + jj;
          int n = n0 + wc * 64 + nt * 16 + ln;
          out[(size_t)m * N + n] = f2b(acc[mt][nt][jj]);
        }
  } else {
#pragma unroll
    for (int mt = 0; mt < 4; ++mt)
#pragma unroll
      for (int nt = 0; nt < 4; ++nt) {
        int s0 = m0 + wr * 64 + mt * 16 + 4 * g;
        int u = n0 + wc * 64 + nt * 16 + ln;
        int b = s0 >> 12, s = s0 & 4095;
        int h = u >> 6, d = u & 63;
        us4 pv;
#pragma unroll
        for (int jj = 0; jj < 4; ++jj) pv[jj] = f2b(acc[mt][nt][jj]);
        *(us4*)&VTo[((size_t)((b * 8 + h) * 64 + d)) * S + s] = pv;
      }
  }
}

// ---------------- output projection GEMM: f32 out ----------------
__global__ __launch_bounds__(256) void gemm_ao_kernel(
    const ushort_t* __restrict__ A, const ushort_t* __restrict__ BT,
    float* __restrict__ out) {
  const int K = 512, N = 512;
  __shared__ ushort_t Al[128 * 64];
  __shared__ ushort_t Bl[128 * 64];

  int tid = threadIdx.x, lane = tid & 63, w = tid >> 6;
  int g = lane >> 4, ln = lane & 15;
  int wr = w >> 1, wc = w & 1;
  int m0 = blockIdx.y * 128;
  int n0 = blockIdx.x * 128;

  f32x4 acc[4][4];
  const f32x4 zz = {0.f, 0.f, 0.f, 0.f};
#pragma unroll
  for (int i = 0; i < 4; ++i)
#pragma unroll
    for (int j = 0; j < 4; ++j) acc[i][j] = zz;

  for (int kt = 0; kt < 8; ++kt) {
    __syncthreads();
#pragma unroll
    for (int i = 0; i < 4; ++i) {
      int p = i * 256 + tid, row = p >> 3, sl = p & 7, sp = sl ^ (row & 7);
      gld_lds16(A + (size_t)(m0 + row) * K + kt * 64 + sp * 8,
                (char*)Al + (i * 256 + (tid & 192)) * 16);
    }
#pragma unroll
    for (int i = 0; i < 4; ++i) {
      int p = i * 256 + tid, row = p >> 3, sl = p & 7, sp = sl ^ (row & 7);
      gld_lds16(BT + (size_t)(n0 + row) * K + kt * 64 + sp * 8,
                (char*)Bl + (i * 256 + (tid & 192)) * 16);
    }
    __syncthreads();

#pragma unroll
    for (int kc = 0; kc < 2; ++kc) {
      short8 af[4], bf[4];
#pragma unroll
      for (int mt = 0; mt < 4; ++mt) {
        int row = wr * 64 + mt * 16 + ln;
        af[mt] = *(const short8*)((char*)Al + row * 128 + (((kc * 4 + g) ^ (row & 7)) * 16));
      }
#pragma unroll
      for (int nt = 0; nt < 4; ++nt) {
        int row = wc * 64 + nt * 16 + ln;
        bf[nt] = *(const short8*)((char*)Bl + row * 128 + (((kc * 4 + g) ^ (row & 7)) * 16));
      }
#pragma unroll
      for (int mt = 0; mt < 4; ++mt)
#pragma unroll
        for (int nt = 0; nt < 4; ++nt)
          acc[mt][nt] = __builtin_amdgcn_mfma_f32_16x16x32_bf16(af[mt], bf[nt], acc[mt][nt], 0, 0, 0);
    }
  }
#pragma unroll
  for (int mt = 0; mt < 4; ++mt)
#pragma unroll
    for (int nt = 0; nt < 4; ++nt)
#pragma unroll
      for (int jj = 0; jj < 4; ++jj) {
        int m = m0 + wr * 64 + mt * 16 + 4 * g + jj;
        int n = n0 + wc * 64 + nt * 16 + ln;
        out[(size_t)m * N + n] = acc[mt][nt][jj];
      }
}

// ---------------- flash attention, kv-sliced waves ----------------
// grid (S/64, H, 2*nparts). 4 waves/block; wave w owns kv rows [w*16, w*16+16)
// of each 64-kv tile and ALL 64 q of the block. Q held in registers (8 short8).
// K/V LDS-read exactly once. PV = ctx^T += V^T·P^T via mfma 16x16x16 whose
// B-frag (col=ln, k=4g+jj) IS the S^T accumulator layout -> P never hits LDS.
// Per-wave partial ctx^T/lrun reduced across waves at kernel end in Kl/Vl space.
__global__ __launch_bounds__(256) void attn_kernel(
    const ushort_t* __restrict__ Qg, const ushort_t* __restrict__ Kg,
    const ushort_t* __restrict__ VTg, ushort_t* __restrict__ Obuf,
    float* __restrict__ Lbuf, int ntiles) {
  const int S = 4096, U = 512;
  const float CSC = 0.125f * 1.44269504089f;   // scale * log2(e)
  int qb = blockIdx.x, h = blockIdx.y;
  int b = blockIdx.z & 1, part = blockIdx.z >> 1;
  int bh = b * 8 + h;
  int tid = threadIdx.x, lane = tid & 63, w = tid >> 6;
  int g = lane >> 4, ln = lane & 15;

  __shared__ __align__(16) char smem[17920];
  ushort_t* Kl = (ushort_t*)smem;             // 8 KB  [64 kv][64 d] swizzled
  ushort_t* Vl = (ushort_t*)(smem + 8192);    // 8 KB  [64 d][64 kv] swizzled
  float* F    = (float*)smem;                 // end-phase alias: [q][d] f32 swz
  float* wred = (float*)(smem + 16384);       // [4][64] per-tile col-max; end: lrun
  float* Msh  = (float*)(smem + 17408);       // [64] tile max; end: running max
  float* Lsum = (float*)(smem + 17664);       // [64] end-phase

  // Q fragments: 4 n-tiles x 2 k-halves, resident all kernel
  short8 qf[4][2];
  {
    const ushort_t* qp0 = Qg + ((size_t)b * S + qb * 64 + ln) * U + h * 64 + g * 8;
#pragma unroll
    for (int n = 0; n < 4; ++n) {
      qf[n][0] = *(const short8*)(qp0 + (size_t)(16 * n) * U);
      qf[n][1] = *(const short8*)(qp0 + (size_t)(16 * n) * U + 32);
    }
  }

  f32x4 acc[4][4];   // [d-tile][q-tile] ctx^T partial (this wave's kv rows)
  const f32x4 zz = {0.f, 0.f, 0.f, 0.f};
#pragma unroll
  for (int i = 0; i < 4; ++i)
#pragma unroll
    for (int j = 0; j < 4; ++j) acc[i][j] = zz;
  float mrun[4], lrun[4];
#pragma unroll
  for (int n = 0; n < 4; ++n) { mrun[n] = -INFINITY; lrun[n] = 0.f; }

  int r = tid >> 3;              // 0..31
  int c8 = (tid & 7) * 8;
  const ushort_t* kbase = Kg + ((size_t)b * S + r) * U + h * 64 + c8;
  const ushort_t* vbase = VTg + ((size_t)(bh * 64 + r)) * S + c8;

  int it0 = part * ntiles;
  for (int ii = 0; ii < ntiles; ++ii) {
    int kv0 = (it0 + ii) * 64;
    uint4 k1 = *(const uint4*)(kbase + (size_t)kv0 * U);
    uint4 k2 = *(const uint4*)(kbase + (size_t)(kv0 + 32) * U);
    uint4 v1 = *(const uint4*)(vbase + kv0);
    uint4 v2 = *(const uint4*)(vbase + (size_t)32 * S + kv0);
    __syncthreads();   // prev tile fully consumed
    {
      int by1 = (r * 128 + c8 * 2) ^ ((r & 7) << 4);
      *(uint4*)((char*)Kl + by1) = k1;
      *(uint4*)((char*)Vl + by1) = v1;
      int r2 = r + 32;
      int by2 = (r2 * 128 + c8 * 2) ^ ((r2 & 7) << 4);
      *(uint4*)((char*)Kl + by2) = k2;
      *(uint4*)((char*)Vl + by2) = v2;
    }
    __syncthreads();   // tile staged

    // ---- S^T slice = K[w*16..+16] . Q^T : 2 ds_read + 8 mfma ----
    int arow = w * 16 + ln;
    short8 kf0 = *(const short8*)((char*)Kl + ((arow * 128 + 16 * g) ^ ((arow & 7) << 4)));
    short8 kf1 = *(const short8*)((char*)Kl + ((arow * 128 + 64 + 16 * g) ^ ((arow & 7) << 4)));
    f32x4 st[4];
#pragma unroll
    for (int n = 0; n < 4; ++n) {
      st[n] = __builtin_amdgcn_mfma_f32_16x16x32_bf16(kf0, qf[n][0], zz, 0, 0, 0);
      st[n] = __builtin_amdgcn_mfma_f32_16x16x32_bf16(kf1, qf[n][1], st[n], 0, 0, 0);
    }

    // ---- wave-partial column max (cols q=16n+ln; rows in jj and g) ----
    float cmax[4];
#pragma unroll
    for (int n = 0; n < 4; ++n) {
      float v = fmaxf(max3f(st[n][0], st[n][1], st[n][2]), st[n][3]);
      v = fmaxf(v, __shfl_xor(v, 16));
      v = fmaxf(v, __shfl_xor(v, 32));
      cmax[n] = v;
    }
    if (g == 0) {
#pragma unroll
      for (int n = 0; n < 4; ++n) wred[w * 64 + 16 * n + ln] = cmax[n];
    }
    __syncthreads();
    // combine across waves (thread-space: q = tid>>2, wave-slot = tid&3)
    {
      int q = tid >> 2;
      float v = wred[(tid & 3) * 64 + q];
      v = fmaxf(v, __shfl_xor(v, 1));
      v = fmaxf(v, __shfl_xor(v, 2));
      if ((tid & 3) == 0) Msh[q] = v;
    }
    __syncthreads();

    // ---- per-col online softmax state (exp2 domain) ----
    float tm[4];
#pragma unroll
    for (int n = 0; n < 4; ++n) tm[n] = Msh[16 * n + ln] * CSC;
    bool need = false;
#pragma unroll
    for (int n = 0; n < 4; ++n) need |= (tm[n] > mrun[n] + 8.0f);
    if (__any(need)) {   // T13 defer-max: deterministic, identical across waves
#pragma unroll
      for (int n = 0; n < 4; ++n) {
        float mn = fmaxf(mrun[n], tm[n]);
        float al = __builtin_amdgcn_exp2f(mrun[n] - mn);
        mrun[n] = mn;
        lrun[n] *= al;
#pragma unroll
        for (int dt = 0; dt < 4; ++dt) acc[dt][n] *= al;
      }
    }

    // ---- exp + in-register P fragments (B-frag of 16x16x16) + col sums ----
    short4v pf[4];
#pragma unroll
    for (int n = 0; n < 4; ++n) {
      float nb = -mrun[n];
      float p0 = __builtin_amdgcn_exp2f(__builtin_fmaf(st[n][0], CSC, nb));
      float p1 = __builtin_amdgcn_exp2f(__builtin_fmaf(st[n][1], CSC, nb));
      float p2 = __builtin_amdgcn_exp2f(__builtin_fmaf(st[n][2], CSC, nb));
      float p3 = __builtin_amdgcn_exp2f(__builtin_fmaf(st[n][3], CSC, nb));
      union { uint_t u[2]; short4v s; } pu;
      pu.u[0] = cvtpk(p0, p1);
      pu.u[1] = cvtpk(p2, p3);
      pf[n] = pu.s;
      float ps = (p0 + p1) + (p2 + p3);
      ps += __shfl_xor(ps, 16);
      ps += __shfl_xor(ps, 32);
      lrun[n] += ps;
    }

    // ---- PV: ctx^T += V^T-frag · P-frag (A-frags shared across n) ----
#pragma unroll
    for (int dt = 0; dt < 4; ++dt) {
      int vrow = dt * 16 + ln;
      short4v vf = *(const short4v*)((char*)Vl +
          ((vrow * 128 + 32 * w + 8 * g) ^ ((vrow & 7) << 4)));
#pragma unroll
      for (int n = 0; n < 4; ++n)
        acc[dt][n] = mfma16(vf, pf[n], acc[dt][n]);
    }
  }

  // ================= end-phase: cross-wave reduction & store =================
  __syncthreads();   // all PV reads of Vl done -> Kl/Vl reusable as F
  if (g == 0) {
#pragma unroll
    for (int n = 0; n < 4; ++n) {
      wred[w * 64 + 16 * n + ln] = lrun[n];
      if (w == 0) Msh[16 * n + ln] = mrun[n];
    }
  }
  // serial ctx^T reduce into F[q][d] (f32, row-q XOR swizzle)
  for (int rw = 0; rw < 4; ++rw) {
    __syncthreads();
    if (w == rw) {
#pragma unroll
      for (int dt = 0; dt < 4; ++dt)
#pragma unroll
        for (int n = 0; n < 4; ++n) {
          int q = 16 * n + ln, d0 = dt * 16 + 4 * g;
          char* fp = (char*)F + (((q * 64 + d0) * 4) ^ ((q & 7) << 4));
          if (rw == 0) *(f32x4*)fp = acc[dt][n];
          else         *(f32x4*)fp = acc[dt][n] + *(const f32x4*)fp;
        }
    }
  }
  __syncthreads();
  // combine lrun across waves; write Lbuf
  {
    int q = tid >> 2;
    float v = wred[(tid & 3) * 64 + q];
    v += __shfl_xor(v, 1);
    v += __shfl_xor(v, 2);
    if ((tid & 3) == 0) {
      Lsum[q] = v;
      Lbuf[part * 65536 + bh * S + qb * 64 + q] = Msh[q] + __log2f(v);
    }
  }
  __syncthreads();
  // normalize & store Obuf[part][bh*S+s][d] bf16
  {
    int q = tid >> 2, dg = (tid & 3) * 16;
    float inv = 1.f / Lsum[q];
    ushort_t* ob = Obuf + (size_t)part * 4194304 +
                   ((size_t)bh * S + qb * 64 + q) * 64 + dg;
#pragma unroll
    for (int c = 0; c < 4; ++c) {
      f32x4 vv = *(const f32x4*)((char*)F +
          (((q * 64 + dg + 4 * c) * 4) ^ ((q & 7) << 4)));
      us4 o;
#pragma unroll
      for (int j = 0; j < 4; ++j) o[j] = f2b(vv[j] * inv);
      *(us4*)(ob + 4 * c) = o;
    }
  }
}

// ---------------- combine partials -> CTX bf16 natural layout ----------------
__global__ void combine_kernel(const ushort_t* __restrict__ Obuf,
                               const float* __restrict__ Lbuf,
                               ushort_t* __restrict__ CTX, int nparts) {
  int tid = threadIdx.x;
  int row = blockIdx.x * 32 + (tid >> 3);   // bh*4096 + s
  int c = (tid & 7) * 8;
  int bh = row >> 12, s = row & 4095;
  int b = bh >> 3, h = bh & 7;

  us4 n0a = *(const us4*)&Obuf[(size_t)row * 64 + c];
  us4 n0b = *(const us4*)&Obuf[(size_t)row * 64 + c + 4];
  float o[8];
  if (nparts == 2) {
    float L0 = Lbuf[row];
    float L1 = Lbuf[65536 + row];
    us4 n1a = *(const us4*)&Obuf[(size_t)(4194304 + row * 64) + c];
    us4 n1b = *(const us4*)&Obuf[(size_t)(4194304 + row * 64) + c + 4];
    float Lm = fmaxf(L0, L1);
    float w0 = __builtin_amdgcn_exp2f(L0 - Lm);
    float w1 = __builtin_amdgcn_exp2f(L1 - Lm);
    float inv = 1.f / (w0 + w1);
    float a0 = w0 * inv, a1 = w1 * inv;
#pragma unroll
    for (int j = 0; j < 4; ++j) {
      o[j]     = a0 * b2f(n0a[j]) + a1 * b2f(n1a[j]);
      o[j + 4] = a0 * b2f(n0b[j]) + a1 * b2f(n1b[j]);
    }
  } else {
#pragma unroll
    for (int j = 0; j < 4; ++j) { o[j] = b2f(n0a[j]); o[j + 4] = b2f(n0b[j]); }
  }
  us4 w0v, w1v;
#pragma unroll
  for (int j = 0; j < 4; ++j) { w0v[j] = f2b(o[j]); w1v[j] = f2b(o[j + 4]); }
  ushort_t* dst = &CTX[((size_t)(b * 4096 + s)) * 512 + h * 64 + c];
  *(us4*)dst = w0v;
  *(us4*)(dst + 4) = w1v;
}

extern "C" void kernel_launch(void* const* d_in, const int* in_sizes, int n_in,
                              void* d_out, int out_size, void* d_ws, size_t ws_size,
                              hipStream_t stream) {
  const float* x  = (const float*)d_in[0];
  const float* Wq = (const float*)d_in[1];
  const float* Wk = (const float*)d_in[2];
  const float* Wv = (const float*)d_in[3];
  const float* Wo = (const float*)d_in[4];
  float* out = (float*)d_out;

  ushort_t* ws  = (ushort_t*)d_ws;
  ushort_t* xb  = ws;                 // 8MB (reused for CTX after gemm_qkv)
  ushort_t* WqT = xb + 4194304;
  ushort_t* WkT = WqT + 262144;
  ushort_t* WvT = WkT + 262144;
  ushort_t* WoT = WvT + 262144;
  ushort_t* Qb  = WoT + 262144;
  ushort_t* Kb  = Qb + 4194304;
  ushort_t* VTb = Kb + 4194304;
  ushort_t* Obuf = VTb + 4194304;     // nparts * 8MB
  ushort_t* CTX = xb;

  int nparts = (ws_size >= 52953088u) ? 2 : 1;
  float* Lbuf = (float*)(Obuf + (size_t)nparts * 4194304);
  int ntiles = 64 / nparts;

  cvt_x_kernel<<<4096, 256, 0, stream>>>(x, xb, 1048576);
  cvt_wt_kernel<<<dim3(64, 1, 4), 256, 0, stream>>>(Wq, Wk, Wv, Wo, WqT, WkT, WvT, WoT);
  gemm_qkv_kernel<<<dim3(4, 64, 3), 256, 0, stream>>>(xb, WqT, WkT, WvT, Qb, Kb, VTb);
  attn_kernel<<<dim3(64, 8, 2 * nparts), 256, 0, stream>>>(Qb, Kb, VTb, Obuf, Lbuf, ntiles);
  combine_kernel<<<2048, 256, 0, stream>>>(Obuf, Lbuf, CTX, nparts);
  gemm_ao_kernel<<<dim3(4, 64), 256, 0, stream>>>(CTX, WoT, out);
}

// Round 8
// 244.806 us; speedup vs baseline: 1.4125x; 1.4125x over previous
//
#include <hip/hip_runtime.h>

typedef __attribute__((ext_vector_type(8))) short short8;
typedef __attribute__((ext_vector_type(4))) float f32x4;
typedef __attribute__((ext_vector_type(4))) unsigned short us4;
typedef unsigned short ushort_t;
typedef unsigned int uint_t;

typedef const __attribute__((address_space(1))) void* gas1;
typedef __attribute__((address_space(3))) void* las3;

// fence: forbid compile-time reordering of LDS ops across this point and
// drain outstanding DS ops (rule #18: asm waitcnt needs sched_barrier after)
#define LDS_FENCE()                                            \
  do {                                                         \
    asm volatile("s_waitcnt lgkmcnt(0)" ::: "memory");         \
    __builtin_amdgcn_sched_barrier(0);                         \
  } while (0)

__device__ __forceinline__ ushort_t f2b(float f) {
  union { float f; uint_t u; } v; v.f = f;
  return (ushort_t)((v.u + 0x7fffu + ((v.u >> 16) & 1u)) >> 16);
}

__device__ __forceinline__ float b2f(ushort_t u) {
  union { uint_t u; float f; } v; v.u = ((uint_t)u) << 16;
  return v.f;
}

// pack 2 f32 -> 2 bf16 in one u32 (RNE) — T12 primitive
__device__ __forceinline__ uint_t cvtpk(float lo, float hi) {
  uint_t r;
  asm("v_cvt_pk_bf16_f32 %0, %1, %2" : "=v"(r) : "v"(lo), "v"(hi));
  return r;
}

__device__ __forceinline__ void gld_lds16(const ushort_t* g, void* l) {
  __builtin_amdgcn_global_load_lds((gas1)g, (las3)l, 16, 0, 0);
}

__device__ __forceinline__ float max3f(float a, float b, float c) {
  return fmaxf(fmaxf(a, b), c);   // clang fuses to v_max3_f32
}

// ---------------- convert x: f32 -> bf16, 4 elems/thread ----------------
__global__ void cvt_x_kernel(const float* __restrict__ x, ushort_t* __restrict__ xb, int n4) {
  int i = blockIdx.x * blockDim.x + threadIdx.x;
  if (i >= n4) return;
  float4 v = ((const float4*)x)[i];
  ushort4 o;
  o.x = f2b(v.x); o.y = f2b(v.y); o.z = f2b(v.z); o.w = f2b(v.w);
  ((ushort4*)xb)[i] = o;
}

// ------- convert + transpose W [512][512] f32 -> WT bf16, LDS-tiled -------
__global__ void cvt_wt_kernel(const float* __restrict__ W0, const float* __restrict__ W1,
                              const float* __restrict__ W2, const float* __restrict__ W3,
                              ushort_t* __restrict__ T0, ushort_t* __restrict__ T1,
                              ushort_t* __restrict__ T2, ushort_t* __restrict__ T3) {
  const float* W; ushort_t* T;
  switch (blockIdx.z) {
    case 0: W = W0; T = T0; break;
    case 1: W = W1; T = T1; break;
    case 2: W = W2; T = T2; break;
    default: W = W3; T = T3; break;
  }
  __shared__ ushort_t Tl[64 * 68];
  int t = threadIdx.x;
  int kt = blockIdx.x & 7, nt = blockIdx.x >> 3;
  int krow = t >> 4;
  int ncol = (t & 15) * 4;
#pragma unroll
  for (int j = 0; j < 4; ++j) {
    int k = j * 16 + krow;
    float4 v = *(const float4*)&W[(size_t)(kt * 64 + k) * 512 + nt * 64 + ncol];
    const float* vf = (const float*)&v;
#pragma unroll
    for (int e = 0; e < 4; ++e)
      Tl[(ncol + e) * 68 + k] = f2b(vf[e]);
  }
  __syncthreads();
#pragma unroll
  for (int j = 0; j < 4; ++j) {
    int f = j * 1024 + t * 4;
    int n = f >> 6, k = f & 63;
    *(ushort4*)&T[(size_t)(nt * 64 + n) * 512 + kt * 64 + k] =
        *(const ushort4*)&Tl[n * 68 + k];
  }
}

// ---------------- QKV projection GEMM, m97-style LDS-staged ----------------
__global__ __launch_bounds__(256) void gemm_qkv_kernel(
    const ushort_t* __restrict__ A,
    const ushort_t* __restrict__ WqT, const ushort_t* __restrict__ WkT,
    const ushort_t* __restrict__ WvT,
    ushort_t* __restrict__ Qo, ushort_t* __restrict__ Ko, ushort_t* __restrict__ VTo) {
  const int K = 512, N = 512, S = 4096;
  const ushort_t* BT; ushort_t* out; int mode;
  switch (blockIdx.z) {
    case 0: BT = WqT; out = Qo;  mode = 0; break;
    case 1: BT = WkT; out = Ko;  mode = 0; break;
    default: BT = WvT; out = VTo; mode = 1; break;
  }
  __shared__ ushort_t Al[128 * 64];
  __shared__ ushort_t Bl[128 * 64];

  int tid = threadIdx.x, lane = tid & 63, w = tid >> 6;
  int g = lane >> 4, ln = lane & 15;
  int wr = w >> 1, wc = w & 1;
  int m0 = blockIdx.y * 128;
  int n0 = blockIdx.x * 128;

  f32x4 acc[4][4];
  const f32x4 zz = {0.f, 0.f, 0.f, 0.f};
#pragma unroll
  for (int i = 0; i < 4; ++i)
#pragma unroll
    for (int j = 0; j < 4; ++j) acc[i][j] = zz;

  for (int kt = 0; kt < 8; ++kt) {
    __syncthreads();
#pragma unroll
    for (int i = 0; i < 4; ++i) {
      int p = i * 256 + tid, row = p >> 3, sl = p & 7, sp = sl ^ (row & 7);
      gld_lds16(A + (size_t)(m0 + row) * K + kt * 64 + sp * 8,
                (char*)Al + (i * 256 + (tid & 192)) * 16);
    }
#pragma unroll
    for (int i = 0; i < 4; ++i) {
      int p = i * 256 + tid, row = p >> 3, sl = p & 7, sp = sl ^ (row & 7);
      gld_lds16(BT + (size_t)(n0 + row) * K + kt * 64 + sp * 8,
                (char*)Bl + (i * 256 + (tid & 192)) * 16);
    }
    __syncthreads();

#pragma unroll
    for (int kc = 0; kc < 2; ++kc) {
      short8 af[4], bf[4];
#pragma unroll
      for (int mt = 0; mt < 4; ++mt) {
        int row = wr * 64 + mt * 16 + ln;
        af[mt] = *(const short8*)((char*)Al + row * 128 + (((kc * 4 + g) ^ (row & 7)) * 16));
      }
#pragma unroll
      for (int nt = 0; nt < 4; ++nt) {
        int row = wc * 64 + nt * 16 + ln;
        bf[nt] = *(const short8*)((char*)Bl + row * 128 + (((kc * 4 + g) ^ (row & 7)) * 16));
      }
#pragma unroll
      for (int mt = 0; mt < 4; ++mt)
#pragma unroll
        for (int nt = 0; nt < 4; ++nt)
          acc[mt][nt] = __builtin_amdgcn_mfma_f32_16x16x32_bf16(af[mt], bf[nt], acc[mt][nt], 0, 0, 0);
    }
  }

  if (mode == 0) {
#pragma unroll
    for (int mt = 0; mt < 4; ++mt)
#pragma unroll
      for (int nt = 0; nt < 4; ++nt)
#pragma unroll
        for (int jj = 0; jj < 4; ++jj) {
          int m = m0 + wr * 64 + mt * 16 + 4 * g + jj;
          int n = n0 + wc * 64 + nt * 16 + ln;
          out[(size_t)m * N + n] = f2b(acc[mt][nt][jj]);
        }
  } else {
#pragma unroll
    for (int mt = 0; mt < 4; ++mt)
#pragma unroll
      for (int nt = 0; nt < 4; ++nt) {
        int s0 = m0 + wr * 64 + mt * 16 + 4 * g;
        int u = n0 + wc * 64 + nt * 16 + ln;
        int b = s0 >> 12, s = s0 & 4095;
        int h = u >> 6, d = u & 63;
        us4 pv;
#pragma unroll
        for (int jj = 0; jj < 4; ++jj) pv[jj] = f2b(acc[mt][nt][jj]);
        *(us4*)&VTo[((size_t)((b * 8 + h) * 64 + d)) * S + s] = pv;
      }
  }
}

// ---------------- output projection GEMM: f32 out ----------------
__global__ __launch_bounds__(256) void gemm_ao_kernel(
    const ushort_t* __restrict__ A, const ushort_t* __restrict__ BT,
    float* __restrict__ out) {
  const int K = 512, N = 512;
  __shared__ ushort_t Al[128 * 64];
  __shared__ ushort_t Bl[128 * 64];

  int tid = threadIdx.x, lane = tid & 63, w = tid >> 6;
  int g = lane >> 4, ln = lane & 15;
  int wr = w >> 1, wc = w & 1;
  int m0 = blockIdx.y * 128;
  int n0 = blockIdx.x * 128;

  f32x4 acc[4][4];
  const f32x4 zz = {0.f, 0.f, 0.f, 0.f};
#pragma unroll
  for (int i = 0; i < 4; ++i)
#pragma unroll
    for (int j = 0; j < 4; ++j) acc[i][j] = zz;

  for (int kt = 0; kt < 8; ++kt) {
    __syncthreads();
#pragma unroll
    for (int i = 0; i < 4; ++i) {
      int p = i * 256 + tid, row = p >> 3, sl = p & 7, sp = sl ^ (row & 7);
      gld_lds16(A + (size_t)(m0 + row) * K + kt * 64 + sp * 8,
                (char*)Al + (i * 256 + (tid & 192)) * 16);
    }
#pragma unroll
    for (int i = 0; i < 4; ++i) {
      int p = i * 256 + tid, row = p >> 3, sl = p & 7, sp = sl ^ (row & 7);
      gld_lds16(BT + (size_t)(n0 + row) * K + kt * 64 + sp * 8,
                (char*)Bl + (i * 256 + (tid & 192)) * 16);
    }
    __syncthreads();

#pragma unroll
    for (int kc = 0; kc < 2; ++kc) {
      short8 af[4], bf[4];
#pragma unroll
      for (int mt = 0; mt < 4; ++mt) {
        int row = wr * 64 + mt * 16 + ln;
        af[mt] = *(const short8*)((char*)Al + row * 128 + (((kc * 4 + g) ^ (row & 7)) * 16));
      }
#pragma unroll
      for (int nt = 0; nt < 4; ++nt) {
        int row = wc * 64 + nt * 16 + ln;
        bf[nt] = *(const short8*)((char*)Bl + row * 128 + (((kc * 4 + g) ^ (row & 7)) * 16));
      }
#pragma unroll
      for (int mt = 0; mt < 4; ++mt)
#pragma unroll
        for (int nt = 0; nt < 4; ++nt)
          acc[mt][nt] = __builtin_amdgcn_mfma_f32_16x16x32_bf16(af[mt], bf[nt], acc[mt][nt], 0, 0, 0);
    }
  }
#pragma unroll
  for (int mt = 0; mt < 4; ++mt)
#pragma unroll
    for (int nt = 0; nt < 4; ++nt)
#pragma unroll
      for (int jj = 0; jj < 4; ++jj) {
        int m = m0 + wr * 64 + mt * 16 + 4 * g + jj;
        int n = n0 + wc * 64 + nt * 16 + ln;
        out[(size_t)m * N + n] = acc[mt][nt][jj];
      }
}

// ---------------- flash attention, KV-split (round-6 structure) ----------------
// grid (S/64, H, 2*nparts); 4 waves/block; wave w owns q rows [qb*64+w*16, +16).
// Round-8 edits: (1) T14 prefetch — K/V tile loaded into regs one tile ahead,
// issued AFTER the staging barrier so HBM latency hides under compute;
// (2) all loop-invariant global pointers / LDS offsets hoisted pre-loop.
__global__ __launch_bounds__(256) void attn_kernel(
    const ushort_t* __restrict__ Qg, const ushort_t* __restrict__ Kg,
    const ushort_t* __restrict__ VTg, ushort_t* __restrict__ Obuf,
    float* __restrict__ Lbuf, int ntiles) {
  const int S = 4096, U = 512;
  const float CSC = 0.125f * 1.44269504089f;   // scale * log2(e)
  int qb = blockIdx.x, h = blockIdx.y;
  int b = blockIdx.z & 1, part = blockIdx.z >> 1;
  int bh = b * 8 + h;
  int tid = threadIdx.x, lane = tid & 63, w = tid >> 6;
  int g = lane >> 4, ln = lane & 15;

  __shared__ ushort_t Kl[64 * 64];
  __shared__ ushort_t Vl[64 * 64];
  __shared__ ushort_t Pl[4][16 * 72];

  const ushort_t* qp = Qg + ((size_t)b * S + qb * 64 + w * 16 + ln) * U + h * 64 + g * 8;
  short8 qf0 = *(const short8*)qp;
  short8 qf1 = *(const short8*)(qp + 32);

  f32x4 acc[4];
  const f32x4 zz = {0.f, 0.f, 0.f, 0.f};
#pragma unroll
  for (int i = 0; i < 4; ++i) acc[i] = zz;
  float mrun = -INFINITY, lrun = 0.f;

  // ---- hoisted invariant addresses ----
  int r = tid >> 3;              // 0..31
  int c8 = (tid & 7) * 8;
  int wby1 = (r * 128 + c8 * 2) ^ ((r & 7) << 4);
  int r2 = r + 32;
  int wby2 = (r2 * 128 + c8 * 2) ^ ((r2 & 7) << 4);

  int foff[4][2];                // shared K/V fragment byte offsets (row mt*16+ln)
#pragma unroll
  for (int m = 0; m < 4; ++m) {
    int row = m * 16 + ln;
#pragma unroll
    for (int hh = 0; hh < 2; ++hh)
      foff[m][hh] = (row * 128 + 64 * hh + 16 * g) ^ ((row & 7) << 4);
  }
  ushort_t* Pw = &Pl[w][0];
  int pwo[4], pro[2];
#pragma unroll
  for (int m = 0; m < 4; ++m) pwo[m] = ln * 72 + m * 16 + 4 * g;
#pragma unroll
  for (int c = 0; c < 2; ++c) pro[c] = ln * 72 + 32 * c + 8 * g;

  int it0 = part * ntiles;
  const ushort_t* kp1 = Kg + ((size_t)b * S + it0 * 64 + r) * U + h * 64 + c8;
  const ushort_t* kp2 = kp1 + (size_t)32 * U;
  const ushort_t* vp1 = VTg + ((size_t)(bh * 64 + r)) * S + it0 * 64 + c8;
  const ushort_t* vp2 = vp1 + (size_t)32 * S;

  // prefetch tile 0
  uint4 k1 = *(const uint4*)kp1;
  uint4 k2 = *(const uint4*)kp2;
  uint4 v1 = *(const uint4*)vp1;
  uint4 v2 = *(const uint4*)vp2;

  for (int ii = 0; ii < ntiles; ++ii) {
    __syncthreads();   // prev tile fully consumed
    *(uint4*)((char*)Kl + wby1) = k1;
    *(uint4*)((char*)Vl + wby1) = v1;
    *(uint4*)((char*)Kl + wby2) = k2;
    *(uint4*)((char*)Vl + wby2) = v2;
    __syncthreads();   // tile staged

    // issue next tile's loads now — they drain during compute (T14)
    if (ii + 1 < ntiles) {
      kp1 += (size_t)64 * U; kp2 += (size_t)64 * U;
      vp1 += 64; vp2 += 64;
      k1 = *(const uint4*)kp1;
      k2 = *(const uint4*)kp2;
      v1 = *(const uint4*)vp1;
      v2 = *(const uint4*)vp2;
    }

    // ---- S^T = K . Q^T  (rows = kv, cols = q) ----
    f32x4 st[4];
#pragma unroll
    for (int m = 0; m < 4; ++m) {
      short8 kf0 = *(const short8*)((char*)Kl + foff[m][0]);
      short8 kf1 = *(const short8*)((char*)Kl + foff[m][1]);
      st[m] = __builtin_amdgcn_mfma_f32_16x16x32_bf16(kf0, qf0, zz, 0, 0, 0);
      st[m] = __builtin_amdgcn_mfma_f32_16x16x32_bf16(kf1, qf1, st[m], 0, 0, 0);
    }

    // ---- online softmax (exp2 domain), v_max3 tree ----
    float t0 = max3f(st[0][0], st[0][1], st[0][2]);
    float t1 = max3f(st[0][3], st[1][0], st[1][1]);
    float t2 = max3f(st[1][2], st[1][3], st[2][0]);
    float t3 = max3f(st[2][1], st[2][2], st[2][3]);
    float t4 = max3f(st[3][0], st[3][1], st[3][2]);
    float smax = fmaxf(max3f(t0, t1, t2), max3f(t3, t4, st[3][3]));
    smax = fmaxf(smax, __shfl_xor(smax, 16));
    smax = fmaxf(smax, __shfl_xor(smax, 32));
    float tmax = smax * CSC;

    float mnew = fmaxf(mrun, tmax);
    if (!__all(tmax <= mrun + 8.0f)) {   // T13 defer-max
      float alpha = __builtin_amdgcn_exp2f(mrun - mnew);
      mrun = mnew;
      lrun *= alpha;
      float av[4];
#pragma unroll
      for (int jj = 0; jj < 4; ++jj) av[jj] = __shfl(alpha, 4 * g + jj);
#pragma unroll
      for (int dt = 0; dt < 4; ++dt)
#pragma unroll
        for (int jj = 0; jj < 4; ++jj) acc[dt][jj] *= av[jj];
    }

    float nb = -mrun;
    float p[16];
    float ps = 0.f;
#pragma unroll
    for (int m = 0; m < 4; ++m)
#pragma unroll
      for (int jj = 0; jj < 4; ++jj) {
        float y = __builtin_amdgcn_exp2f(__builtin_fmaf(st[m][jj], CSC, nb));
        p[m * 4 + jj] = y;
        ps += y;
      }
    ps += __shfl_xor(ps, 16);
    ps += __shfl_xor(ps, 32);
    lrun += ps;

#pragma unroll
    for (int m = 0; m < 4; ++m) {
      uint2 pv;
      pv.x = cvtpk(p[m * 4 + 0], p[m * 4 + 1]);
      pv.y = cvtpk(p[m * 4 + 2], p[m * 4 + 3]);
      *(uint2*)&Pw[pwo[m]] = pv;
    }
    LDS_FENCE();

    // ---- PV: ctx += P . V ----
#pragma unroll
    for (int c = 0; c < 2; ++c) {
      short8 pf = *(const short8*)&Pw[pro[c]];
#pragma unroll
      for (int dt = 0; dt < 4; ++dt) {
        short8 vf = *(const short8*)((char*)Vl + foff[dt][c]);
        acc[dt] = __builtin_amdgcn_mfma_f32_16x16x32_bf16(pf, vf, acc[dt], 0, 0, 0);
      }
    }
  }

  // store normalized partial + log2 weight
  float inv_l = 1.f / lrun;
  float lv[4];
#pragma unroll
  for (int jj = 0; jj < 4; ++jj) lv[jj] = __shfl(inv_l, 4 * g + jj);
  ushort_t* ob = Obuf + (size_t)part * 4194304 + ((size_t)bh * S) * 64;
#pragma unroll
  for (int dt = 0; dt < 4; ++dt)
#pragma unroll
    for (int jj = 0; jj < 4; ++jj) {
      int s = qb * 64 + w * 16 + 4 * g + jj;
      int d = dt * 16 + ln;
      ob[(size_t)s * 64 + d] = f2b(acc[dt][jj] * lv[jj]);
    }
  if (g == 0) {
    int s = qb * 64 + w * 16 + ln;
    Lbuf[part * 65536 + bh * S + s] = mrun + __log2f(lrun);
  }
}

// ---------------- combine partials -> CTX bf16 natural layout ----------------
__global__ void combine_kernel(const ushort_t* __restrict__ Obuf,
                               const float* __restrict__ Lbuf,
                               ushort_t* __restrict__ CTX, int nparts) {
  int tid = threadIdx.x;
  int row = blockIdx.x * 32 + (tid >> 3);   // bh*4096 + s
  int c = (tid & 7) * 8;
  int bh = row >> 12, s = row & 4095;
  int b = bh >> 3, h = bh & 7;

  us4 n0a = *(const us4*)&Obuf[(size_t)row * 64 + c];
  us4 n0b = *(const us4*)&Obuf[(size_t)row * 64 + c + 4];
  float o[8];
  if (nparts == 2) {
    float L0 = Lbuf[row];
    float L1 = Lbuf[65536 + row];
    us4 n1a = *(const us4*)&Obuf[(size_t)(4194304 + row * 64) + c];
    us4 n1b = *(const us4*)&Obuf[(size_t)(4194304 + row * 64) + c + 4];
    float Lm = fmaxf(L0, L1);
    float w0 = __builtin_amdgcn_exp2f(L0 - Lm);
    float w1 = __builtin_amdgcn_exp2f(L1 - Lm);
    float inv = 1.f / (w0 + w1);
    float a0 = w0 * inv, a1 = w1 * inv;
#pragma unroll
    for (int j = 0; j < 4; ++j) {
      o[j]     = a0 * b2f(n0a[j]) + a1 * b2f(n1a[j]);
      o[j + 4] = a0 * b2f(n0b[j]) + a1 * b2f(n1b[j]);
    }
  } else {
#pragma unroll
    for (int j = 0; j < 4; ++j) { o[j] = b2f(n0a[j]); o[j + 4] = b2f(n0b[j]); }
  }
  us4 w0v, w1v;
#pragma unroll
  for (int j = 0; j < 4; ++j) { w0v[j] = f2b(o[j]); w1v[j] = f2b(o[j + 4]); }
  ushort_t* dst = &CTX[((size_t)(b * 4096 + s)) * 512 + h * 64 + c];
  *(us4*)dst = w0v;
  *(us4*)(dst + 4) = w1v;
}

extern "C" void kernel_launch(void* const* d_in, const int* in_sizes, int n_in,
                              void* d_out, int out_size, void* d_ws, size_t ws_size,
                              hipStream_t stream) {
  const float* x  = (const float*)d_in[0];
  const float* Wq = (const float*)d_in[1];
  const float* Wk = (const float*)d_in[2];
  const float* Wv = (const float*)d_in[3];
  const float* Wo = (const float*)d_in[4];
  float* out = (float*)d_out;

  ushort_t* ws  = (ushort_t*)d_ws;
  ushort_t* xb  = ws;                 // 8MB (reused for CTX after gemm_qkv)
  ushort_t* WqT = xb + 4194304;
  ushort_t* WkT = WqT + 262144;
  ushort_t* WvT = WkT + 262144;
  ushort_t* WoT = WvT + 262144;
  ushort_t* Qb  = WoT + 262144;
  ushort_t* Kb  = Qb + 4194304;
  ushort_t* VTb = Kb + 4194304;
  ushort_t* Obuf = VTb + 4194304;     // nparts * 8MB
  ushort_t* CTX = xb;

  int nparts = (ws_size >= 52953088u) ? 2 : 1;
  float* Lbuf = (float*)(Obuf + (size_t)nparts * 4194304);
  int ntiles = 64 / nparts;

  cvt_x_kernel<<<4096, 256, 0, stream>>>(x, xb, 1048576);
  cvt_wt_kernel<<<dim3(64, 1, 4), 256, 0, stream>>>(Wq, Wk, Wv, Wo, WqT, WkT, WvT, WoT);
  gemm_qkv_kernel<<<dim3(4, 64, 3), 256, 0, stream>>>(xb, WqT, WkT, WvT, Qb, Kb, VTb);
  attn_kernel<<<dim3(64, 8, 2 * nparts), 256, 0, stream>>>(Qb, Kb, VTb, Obuf, Lbuf, ntiles);
  combine_kernel<<<2048, 256, 0, stream>>>(Obuf, Lbuf, CTX, nparts);
  gemm_ao_kernel<<<dim3(4, 64), 256, 0, stream>>>(CTX, WoT, out);
}

// Round 11
// 215.541 us; speedup vs baseline: 1.6043x; 1.1358x over previous
//
#include <hip/hip_runtime.h>

typedef __attribute__((ext_vector_type(8))) short short8;
typedef __attribute__((ext_vector_type(4))) float f32x4;
typedef __attribute__((ext_vector_type(16))) float f32x16;
typedef __attribute__((ext_vector_type(4))) unsigned short us4;
typedef unsigned short ushort_t;
typedef unsigned int uint_t;

typedef const __attribute__((address_space(1))) void* gas1;
typedef __attribute__((address_space(3))) void* las3;

__device__ __forceinline__ ushort_t f2b(float f) {
  union { float f; uint_t u; } v; v.f = f;
  return (ushort_t)((v.u + 0x7fffu + ((v.u >> 16) & 1u)) >> 16);
}

__device__ __forceinline__ float b2f(ushort_t u) {
  union { uint_t u; float f; } v; v.u = ((uint_t)u) << 16;
  return v.f;
}

// pack 2 f32 -> 2 bf16 in one u32 (RNE); low half = first arg (validated r5-r8)
__device__ __forceinline__ uint_t cvtpk(float lo, float hi) {
  uint_t r;
  asm("v_cvt_pk_bf16_f32 %0, %1, %2" : "=v"(r) : "v"(lo), "v"(hi));
  return r;
}

__device__ __forceinline__ void gld_lds16(const ushort_t* g, void* l) {
  __builtin_amdgcn_global_load_lds((gas1)g, (las3)l, 16, 0, 0);
}

__device__ __forceinline__ float max3f(float a, float b, float c) {
  return fmaxf(fmaxf(a, b), c);   // clang fuses to v_max3_f32
}

__device__ __forceinline__ f32x16 mfma32(short8 a, short8 b, f32x16 c) {
  return __builtin_amdgcn_mfma_f32_32x32x16_bf16(a, b, c, 0, 0, 0);
}

// ---------------- convert x: f32 -> bf16, 4 elems/thread ----------------
__global__ void cvt_x_kernel(const float* __restrict__ x, ushort_t* __restrict__ xb, int n4) {
  int i = blockIdx.x * blockDim.x + threadIdx.x;
  if (i >= n4) return;
  float4 v = ((const float4*)x)[i];
  ushort4 o;
  o.x = f2b(v.x); o.y = f2b(v.y); o.z = f2b(v.z); o.w = f2b(v.w);
  ((ushort4*)xb)[i] = o;
}

// ------- convert + transpose W [512][512] f32 -> WT bf16, LDS-tiled -------
__global__ void cvt_wt_kernel(const float* __restrict__ W0, const float* __restrict__ W1,
                              const float* __restrict__ W2, const float* __restrict__ W3,
                              ushort_t* __restrict__ T0, ushort_t* __restrict__ T1,
                              ushort_t* __restrict__ T2, ushort_t* __restrict__ T3) {
  const float* W; ushort_t* T;
  switch (blockIdx.z) {
    case 0: W = W0; T = T0; break;
    case 1: W = W1; T = T1; break;
    case 2: W = W2; T = T2; break;
    default: W = W3; T = T3; break;
  }
  __shared__ ushort_t Tl[64 * 68];
  int t = threadIdx.x;
  int kt = blockIdx.x & 7, nt = blockIdx.x >> 3;
  int krow = t >> 4;
  int ncol = (t & 15) * 4;
#pragma unroll
  for (int j = 0; j < 4; ++j) {
    int k = j * 16 + krow;
    float4 v = *(const float4*)&W[(size_t)(kt * 64 + k) * 512 + nt * 64 + ncol];
    const float* vf = (const float*)&v;
#pragma unroll
    for (int e = 0; e < 4; ++e)
      Tl[(ncol + e) * 68 + k] = f2b(vf[e]);
  }
  __syncthreads();
#pragma unroll
  for (int j = 0; j < 4; ++j) {
    int f = j * 1024 + t * 4;
    int n = f >> 6, k = f & 63;
    *(ushort4*)&T[(size_t)(nt * 64 + n) * 512 + kt * 64 + k] =
        *(const ushort4*)&Tl[n * 68 + k];
  }
}

// ---------------- QKV projection GEMM, m97-style LDS-staged ----------------
__global__ __launch_bounds__(256) void gemm_qkv_kernel(
    const ushort_t* __restrict__ A,
    const ushort_t* __restrict__ WqT, const ushort_t* __restrict__ WkT,
    const ushort_t* __restrict__ WvT,
    ushort_t* __restrict__ Qo, ushort_t* __restrict__ Ko, ushort_t* __restrict__ VTo) {
  const int K = 512, N = 512, S = 4096;
  const ushort_t* BT; ushort_t* out; int mode;
  switch (blockIdx.z) {
    case 0: BT = WqT; out = Qo;  mode = 0; break;
    case 1: BT = WkT; out = Ko;  mode = 0; break;
    default: BT = WvT; out = VTo; mode = 1; break;
  }
  __shared__ ushort_t Al[128 * 64];
  __shared__ ushort_t Bl[128 * 64];

  int tid = threadIdx.x, lane = tid & 63, w = tid >> 6;
  int g = lane >> 4, ln = lane & 15;
  int wr = w >> 1, wc = w & 1;
  int m0 = blockIdx.y * 128;
  int n0 = blockIdx.x * 128;

  f32x4 acc[4][4];
  const f32x4 zz = {0.f, 0.f, 0.f, 0.f};
#pragma unroll
  for (int i = 0; i < 4; ++i)
#pragma unroll
    for (int j = 0; j < 4; ++j) acc[i][j] = zz;

  for (int kt = 0; kt < 8; ++kt) {
    __syncthreads();
#pragma unroll
    for (int i = 0; i < 4; ++i) {
      int p = i * 256 + tid, row = p >> 3, sl = p & 7, sp = sl ^ (row & 7);
      gld_lds16(A + (size_t)(m0 + row) * K + kt * 64 + sp * 8,
                (char*)Al + (i * 256 + (tid & 192)) * 16);
    }
#pragma unroll
    for (int i = 0; i < 4; ++i) {
      int p = i * 256 + tid, row = p >> 3, sl = p & 7, sp = sl ^ (row & 7);
      gld_lds16(BT + (size_t)(n0 + row) * K + kt * 64 + sp * 8,
                (char*)Bl + (i * 256 + (tid & 192)) * 16);
    }
    __syncthreads();

#pragma unroll
    for (int kc = 0; kc < 2; ++kc) {
      short8 af[4], bf[4];
#pragma unroll
      for (int mt = 0; mt < 4; ++mt) {
        int row = wr * 64 + mt * 16 + ln;
        af[mt] = *(const short8*)((char*)Al + row * 128 + (((kc * 4 + g) ^ (row & 7)) * 16));
      }
#pragma unroll
      for (int nt = 0; nt < 4; ++nt) {
        int row = wc * 64 + nt * 16 + ln;
        bf[nt] = *(const short8*)((char*)Bl + row * 128 + (((kc * 4 + g) ^ (row & 7)) * 16));
      }
#pragma unroll
      for (int mt = 0; mt < 4; ++mt)
#pragma unroll
        for (int nt = 0; nt < 4; ++nt)
          acc[mt][nt] = __builtin_amdgcn_mfma_f32_16x16x32_bf16(af[mt], bf[nt], acc[mt][nt], 0, 0, 0);
    }
  }

  if (mode == 0) {
#pragma unroll
    for (int mt = 0; mt < 4; ++mt)
#pragma unroll
      for (int nt = 0; nt < 4; ++nt)
#pragma unroll
        for (int jj = 0; jj < 4; ++jj) {
          int m = m0 + wr * 64 + mt * 16 + 4 * g + jj;
          int n = n0 + wc * 64 + nt * 16 + ln;
          out[(size_t)m * N + n] = f2b(acc[mt][nt][jj]);
        }
  } else {
#pragma unroll
    for (int mt = 0; mt < 4; ++mt)
#pragma unroll
      for (int nt = 0; nt < 4; ++nt) {
        int s0 = m0 + wr * 64 + mt * 16 + 4 * g;
        int u = n0 + wc * 64 + nt * 16 + ln;
        int b = s0 >> 12, s = s0 & 4095;
        int h = u >> 6, d = u & 63;
        us4 pv;
#pragma unroll
        for (int jj = 0; jj < 4; ++jj) pv[jj] = f2b(acc[mt][nt][jj]);
        *(us4*)&VTo[((size_t)((b * 8 + h) * 64 + d)) * S + s] = pv;
      }
  }
}

// ---------------- output projection GEMM: f32 out ----------------
__global__ __launch_bounds__(256) void gemm_ao_kernel(
    const ushort_t* __restrict__ A, const ushort_t* __restrict__ BT,
    float* __restrict__ out) {
  const int K = 512, N = 512;
  __shared__ ushort_t Al[128 * 64];
  __shared__ ushort_t Bl[128 * 64];

  int tid = threadIdx.x, lane = tid & 63, w = tid >> 6;
  int g = lane >> 4, ln = lane & 15;
  int wr = w >> 1, wc = w & 1;
  int m0 = blockIdx.y * 128;
  int n0 = blockIdx.x * 128;

  f32x4 acc[4][4];
  const f32x4 zz = {0.f, 0.f, 0.f, 0.f};
#pragma unroll
  for (int i = 0; i < 4; ++i)
#pragma unroll
    for (int j = 0; j < 4; ++j) acc[i][j] = zz;

  for (int kt = 0; kt < 8; ++kt) {
    __syncthreads();
#pragma unroll
    for (int i = 0; i < 4; ++i) {
      int p = i * 256 + tid, row = p >> 3, sl = p & 7, sp = sl ^ (row & 7);
      gld_lds16(A + (size_t)(m0 + row) * K + kt * 64 + sp * 8,
                (char*)Al + (i * 256 + (tid & 192)) * 16);
    }
#pragma unroll
    for (int i = 0; i < 4; ++i) {
      int p = i * 256 + tid, row = p >> 3, sl = p & 7, sp = sl ^ (row & 7);
      gld_lds16(BT + (size_t)(n0 + row) * K + kt * 64 + sp * 8,
                (char*)Bl + (i * 256 + (tid & 192)) * 16);
    }
    __syncthreads();

#pragma unroll
    for (int kc = 0; kc < 2; ++kc) {
      short8 af[4], bf[4];
#pragma unroll
      for (int mt = 0; mt < 4; ++mt) {
        int row = wr * 64 + mt * 16 + ln;
        af[mt] = *(const short8*)((char*)Al + row * 128 + (((kc * 4 + g) ^ (row & 7)) * 16));
      }
#pragma unroll
      for (int nt = 0; nt < 4; ++nt) {
        int row = wc * 64 + nt * 16 + ln;
        bf[nt] = *(const short8*)((char*)Bl + row * 128 + (((kc * 4 + g) ^ (row & 7)) * 16));
      }
#pragma unroll
      for (int mt = 0; mt < 4; ++mt)
#pragma unroll
        for (int nt = 0; nt < 4; ++nt)
          acc[mt][nt] = __builtin_amdgcn_mfma_f32_16x16x32_bf16(af[mt], bf[nt], acc[mt][nt], 0, 0, 0);
    }
  }
#pragma unroll
  for (int mt = 0; mt < 4; ++mt)
#pragma unroll
    for (int nt = 0; nt < 4; ++nt)
#pragma unroll
      for (int jj = 0; jj < 4; ++jj) {
        int m = m0 + wr * 64 + mt * 16 + 4 * g + jj;
        int n = n0 + wc * 64 + nt * 16 + ln;
        out[(size_t)m * N + n] = acc[mt][nt][jj];
      }
}

// ---------------- flash attention: 8-wave, 32 q/wave, 32x32 MFMA ----------------
// grid (S/256, H, 2*nparts); 512 threads. Wave w owns q [qb*256+w*32, +32).
// Swapped QK^T (A=K from LDS, B=Q in regs): contiguous loads both sides
// (operand-invariant). PV: B = P built DIRECTLY from the S^T C/D regs (4 cvtpk,
// NO cross-lane ops); A = V^T loaded as two b64 chunks at 4*hi offsets so that
// m_A == m_B (operand-invariance guarantees correctness for any shared k-map).
// Pair reductions (lane <-> lane^32) via validated __shfl_xor(.,32).
__global__ __launch_bounds__(512, 4) void attn_kernel(
    const ushort_t* __restrict__ Qg, const ushort_t* __restrict__ Kg,
    const ushort_t* __restrict__ VTg, ushort_t* __restrict__ Obuf,
    float* __restrict__ Lbuf, int ntiles) {
  const int S = 4096, U = 512;
  const float CSC = 0.125f * 1.44269504089f;   // scale * log2(e)
  int qb = blockIdx.x, h = blockIdx.y;
  int b = blockIdx.z & 1, part = blockIdx.z >> 1;
  int bh = b * 8 + h;
  int tid = threadIdx.x, lane = tid & 63, w = tid >> 6;
  int lq = lane & 31, hi = lane >> 5;
  int lx = (lq & 7) << 4;              // row-XOR term (same for lq and 32+lq)

  __shared__ ushort_t Kl[64 * 64];     // [kv][d]  8 KB, XOR-swizzled rows
  __shared__ ushort_t Vl[64 * 64];     // [d][kv]  8 KB, XOR-swizzled rows

  // Q B-frags: contiguous 8 elems, matching K A-frag contiguous load
  int qrow = qb * 256 + w * 32 + lq;
  const ushort_t* qp = Qg + ((size_t)b * S + qrow) * U + h * 64 + hi * 8;
  short8 qf[4];
#pragma unroll
  for (int s = 0; s < 4; ++s) qf[s] = *(const short8*)(qp + 16 * s);

  f32x16 acc0 = {}, acc1 = {};         // ctx^T: col=q=lq, rows d (2 d-tiles)
  float mrun = -INFINITY, lrun = 0.f;

  // staging: 512 threads, 1 uint4 each for K and V
  int r = tid >> 3, c8 = (tid & 7) * 8;
  int wby = (r * 128 + c8 * 2) ^ ((r & 7) << 4);
  int it0 = part * ntiles;
  const ushort_t* kp = Kg + ((size_t)b * S + it0 * 64 + r) * U + h * 64 + c8;
  const ushort_t* vp = VTg + ((size_t)(bh * 64 + r)) * S + it0 * 64 + c8;

  uint4 kst = *(const uint4*)kp;       // prefetch tile 0
  uint4 vst = *(const uint4*)vp;

#define KREAD(rowv, colb) \
  (*(const short8*)((char*)Kl + ((((rowv) * 128) + (colb)) ^ lx)))

  // V^T A-frag for PV k-step t: slots j=0..3 <- kv 16t+4hi+(0..3),
  // j=4..7 <- kv 16t+8+4hi+(0..3)  => matches P's native C/D distribution.
#define VREAD2(rowv, t, vout)                                             \
  {                                                                       \
    int base_ = (rowv) * 128 + 32 * (t) + 8 * hi;                         \
    uint2 lo_ = *(const uint2*)((char*)Vl + (base_ ^ lx));                \
    uint2 hi_ = *(const uint2*)((char*)Vl + ((base_ + 16) ^ lx));         \
    union { uint_t u[4]; short8 s; } vu_;                                 \
    vu_.u[0] = lo_.x; vu_.u[1] = lo_.y; vu_.u[2] = hi_.x; vu_.u[3] = hi_.y; \
    vout = vu_.s;                                                         \
  }

  // P B-frag: native C/D order, no cross-lane exchange
#define MKPF(stv, ks, pfout)                                      \
  {                                                               \
    union { uint_t u[4]; short8 s; } pu;                          \
    pu.u[0] = cvtpk(stv[8 * ks + 0], stv[8 * ks + 1]);            \
    pu.u[1] = cvtpk(stv[8 * ks + 2], stv[8 * ks + 3]);            \
    pu.u[2] = cvtpk(stv[8 * ks + 4], stv[8 * ks + 5]);            \
    pu.u[3] = cvtpk(stv[8 * ks + 6], stv[8 * ks + 7]);            \
    pfout = pu.s;                                                 \
  }

  for (int ii = 0; ii < ntiles; ++ii) {
    __syncthreads();                   // prev tile fully consumed
    *(uint4*)((char*)Kl + wby) = kst;
    *(uint4*)((char*)Vl + wby) = vst;
    __syncthreads();                   // tile staged
    if (ii + 1 < ntiles) {             // T14: next loads drain under compute
      kp += (size_t)64 * U;
      vp += 64;
      kst = *(const uint4*)kp;
      vst = *(const uint4*)vp;
    }

    // ---- S^T = K . Q^T : rows=kv (2 chunks of 32), cols=q ----
    f32x16 st0 = {}, st1 = {};
#pragma unroll
    for (int s = 0; s < 4; ++s)
      st0 = mfma32(KREAD(lq, 32 * s + 16 * hi), qf[s], st0);
#pragma unroll
    for (int s = 0; s < 4; ++s)
      st1 = mfma32(KREAD(32 + lq, 32 * s + 16 * hi), qf[s], st1);

    // ---- softmax (exp2 domain): in-register max tree + shfl_xor(32) ----
    float a0 = max3f(st0[0], st0[1], st0[2]);
    float a1 = max3f(st0[3], st0[4], st0[5]);
    float a2 = max3f(st0[6], st0[7], st0[8]);
    float a3 = max3f(st0[9], st0[10], st0[11]);
    float a4 = max3f(st0[12], st0[13], st0[14]);
    float a5 = max3f(st0[15], st1[0], st1[1]);
    float a6 = max3f(st1[2], st1[3], st1[4]);
    float a7 = max3f(st1[5], st1[6], st1[7]);
    float a8 = max3f(st1[8], st1[9], st1[10]);
    float a9 = max3f(st1[11], st1[12], st1[13]);
    float aa = fmaxf(st1[14], st1[15]);
    float smax = fmaxf(fmaxf(max3f(a0, a1, a2), max3f(a3, a4, a5)),
                       fmaxf(max3f(a6, a7, a8), fmaxf(a9, aa)));
    float tmax = fmaxf(smax, __shfl_xor(smax, 32)) * CSC;

    float mnew = fmaxf(mrun, tmax);
    if (!__all(tmax <= mrun + 8.0f)) {   // T13 defer-max
      float alpha = __builtin_amdgcn_exp2f(mrun - mnew);
      mrun = mnew;
      lrun *= alpha;
#pragma unroll
      for (int i = 0; i < 16; ++i) { acc0[i] *= alpha; acc1[i] *= alpha; }
    }

    float nb = -mrun;
    float ps = 0.f;
#pragma unroll
    for (int i = 0; i < 16; ++i) {
      float y0 = __builtin_amdgcn_exp2f(__builtin_fmaf(st0[i], CSC, nb));
      float y1 = __builtin_amdgcn_exp2f(__builtin_fmaf(st1[i], CSC, nb));
      st0[i] = y0; st1[i] = y1;
      ps += y0 + y1;
    }
    ps += __shfl_xor(ps, 32);
    lrun += ps;

    // ---- PV: ctx^T += V^T-frag . P-frag (m_A == m_B by construction) ----
    short8 pf, vf;
    MKPF(st0, 0, pf);
    VREAD2(lq, 0, vf);      acc0 = mfma32(vf, pf, acc0);
    VREAD2(32 + lq, 0, vf); acc1 = mfma32(vf, pf, acc1);
    MKPF(st0, 1, pf);
    VREAD2(lq, 1, vf);      acc0 = mfma32(vf, pf, acc0);
    VREAD2(32 + lq, 1, vf); acc1 = mfma32(vf, pf, acc1);
    MKPF(st1, 0, pf);
    VREAD2(lq, 2, vf);      acc0 = mfma32(vf, pf, acc0);
    VREAD2(32 + lq, 2, vf); acc1 = mfma32(vf, pf, acc1);
    MKPF(st1, 1, pf);
    VREAD2(lq, 3, vf);      acc0 = mfma32(vf, pf, acc0);
    VREAD2(32 + lq, 3, vf); acc1 = mfma32(vf, pf, acc1);
  }

  // ---- store normalized partial (ctx^T rows d -> Obuf[s][d]) + log2 weight ----
  float inv = 1.f / lrun;
  ushort_t* ob = Obuf + (size_t)part * 4194304 +
                 ((size_t)bh * S + qb * 256 + w * 32 + lq) * 64;
#pragma unroll
  for (int g4 = 0; g4 < 4; ++g4) {     // d = 8*g4 + 4*hi + (0..3)
    uint2 o;
    o.x = cvtpk(acc0[4 * g4 + 0] * inv, acc0[4 * g4 + 1] * inv);
    o.y = cvtpk(acc0[4 * g4 + 2] * inv, acc0[4 * g4 + 3] * inv);
    *(uint2*)(ob + 8 * g4 + 4 * hi) = o;
  }
#pragma unroll
  for (int g4 = 0; g4 < 4; ++g4) {     // d = 32 + 8*g4 + 4*hi + (0..3)
    uint2 o;
    o.x = cvtpk(acc1[4 * g4 + 0] * inv, acc1[4 * g4 + 1] * inv);
    o.y = cvtpk(acc1[4 * g4 + 2] * inv, acc1[4 * g4 + 3] * inv);
    *(uint2*)(ob + 32 + 8 * g4 + 4 * hi) = o;
  }
  if (hi == 0)
    Lbuf[part * 65536 + bh * S + qb * 256 + w * 32 + lq] = mrun + __log2f(lrun);
#undef KREAD
#undef VREAD2
#undef MKPF
}

// ---------------- combine partials -> CTX bf16 natural layout ----------------
__global__ void combine_kernel(const ushort_t* __restrict__ Obuf,
                               const float* __restrict__ Lbuf,
                               ushort_t* __restrict__ CTX, int nparts) {
  int tid = threadIdx.x;
  int row = blockIdx.x * 32 + (tid >> 3);   // bh*4096 + s
  int c = (tid & 7) * 8;
  int bh = row >> 12, s = row & 4095;
  int b = bh >> 3, h = bh & 7;

  us4 n0a = *(const us4*)&Obuf[(size_t)row * 64 + c];
  us4 n0b = *(const us4*)&Obuf[(size_t)row * 64 + c + 4];
  float o[8];
  if (nparts == 2) {
    float L0 = Lbuf[row];
    float L1 = Lbuf[65536 + row];
    us4 n1a = *(const us4*)&Obuf[(size_t)(4194304 + row * 64) + c];
    us4 n1b = *(const us4*)&Obuf[(size_t)(4194304 + row * 64) + c + 4];
    float Lm = fmaxf(L0, L1);
    float w0 = __builtin_amdgcn_exp2f(L0 - Lm);
    float w1 = __builtin_amdgcn_exp2f(L1 - Lm);
    float inv = 1.f / (w0 + w1);
    float a0 = w0 * inv, a1 = w1 * inv;
#pragma unroll
    for (int j = 0; j < 4; ++j) {
      o[j]     = a0 * b2f(n0a[j]) + a1 * b2f(n1a[j]);
      o[j + 4] = a0 * b2f(n0b[j]) + a1 * b2f(n1b[j]);
    }
  } else {
#pragma unroll
    for (int j = 0; j < 4; ++j) { o[j] = b2f(n0a[j]); o[j + 4] = b2f(n0b[j]); }
  }
  us4 w0v, w1v;
#pragma unroll
  for (int j = 0; j < 4; ++j) { w0v[j] = f2b(o[j]); w1v[j] = f2b(o[j + 4]); }
  ushort_t* dst = &CTX[((size_t)(b * 4096 + s)) * 512 + h * 64 + c];
  *(us4*)dst = w0v;
  *(us4*)(dst + 4) = w1v;
}

extern "C" void kernel_launch(void* const* d_in, const int* in_sizes, int n_in,
                              void* d_out, int out_size, void* d_ws, size_t ws_size,
                              hipStream_t stream) {
  const float* x  = (const float*)d_in[0];
  const float* Wq = (const float*)d_in[1];
  const float* Wk = (const float*)d_in[2];
  const float* Wv = (const float*)d_in[3];
  const float* Wo = (const float*)d_in[4];
  float* out = (float*)d_out;

  ushort_t* ws  = (ushort_t*)d_ws;
  ushort_t* xb  = ws;                 // 8MB (reused for CTX after gemm_qkv)
  ushort_t* WqT = xb + 4194304;
  ushort_t* WkT = WqT + 262144;
  ushort_t* WvT = WkT + 262144;
  ushort_t* WoT = WvT + 262144;
  ushort_t* Qb  = WoT + 262144;
  ushort_t* Kb  = Qb + 4194304;
  ushort_t* VTb = Kb + 4194304;
  ushort_t* Obuf = VTb + 4194304;     // nparts * 8MB
  ushort_t* CTX = xb;

  int nparts = (ws_size >= 52953088u) ? 2 : 1;
  float* Lbuf = (float*)(Obuf + (size_t)nparts * 4194304);
  int ntiles = 64 / nparts;

  cvt_x_kernel<<<4096, 256, 0, stream>>>(x, xb, 1048576);
  cvt_wt_kernel<<<dim3(64, 1, 4), 256, 0, stream>>>(Wq, Wk, Wv, Wo, WqT, WkT, WvT, WoT);
  gemm_qkv_kernel<<<dim3(4, 64, 3), 256, 0, stream>>>(xb, WqT, WkT, WvT, Qb, Kb, VTb);
  attn_kernel<<<dim3(16, 8, 2 * nparts), 512, 0, stream>>>(Qb, Kb, VTb, Obuf, Lbuf, ntiles);
  combine_kernel<<<2048, 256, 0, stream>>>(Obuf, Lbuf, CTX, nparts);
  gemm_ao_kernel<<<dim3(4, 64), 256, 0, stream>>>(CTX, WoT, out);
}

// Round 12
// 214.334 us; speedup vs baseline: 1.6133x; 1.0056x over previous
//
#include <hip/hip_runtime.h>

typedef __attribute__((ext_vector_type(8))) short short8;
typedef __attribute__((ext_vector_type(4))) float f32x4;
typedef __attribute__((ext_vector_type(16))) float f32x16;
typedef __attribute__((ext_vector_type(4))) unsigned short us4;
typedef unsigned short ushort_t;
typedef unsigned int uint_t;

typedef const __attribute__((address_space(1))) void* gas1;
typedef __attribute__((address_space(3))) void* las3;

__device__ __forceinline__ ushort_t f2b(float f) {
  union { float f; uint_t u; } v; v.f = f;
  return (ushort_t)((v.u + 0x7fffu + ((v.u >> 16) & 1u)) >> 16);
}

__device__ __forceinline__ float b2f(ushort_t u) {
  union { uint_t u; float f; } v; v.u = ((uint_t)u) << 16;
  return v.f;
}

// pack 2 f32 -> 2 bf16 in one u32 (RNE); low half = first arg (validated r5-r11)
__device__ __forceinline__ uint_t cvtpk(float lo, float hi) {
  uint_t r;
  asm("v_cvt_pk_bf16_f32 %0, %1, %2" : "=v"(r) : "v"(lo), "v"(hi));
  return r;
}

__device__ __forceinline__ void gld_lds16(const ushort_t* g, void* l) {
  __builtin_amdgcn_global_load_lds((gas1)g, (las3)l, 16, 0, 0);
}

__device__ __forceinline__ float max3f(float a, float b, float c) {
  return fmaxf(fmaxf(a, b), c);   // clang fuses to v_max3_f32
}

__device__ __forceinline__ f32x16 mfma32(short8 a, short8 b, f32x16 c) {
  return __builtin_amdgcn_mfma_f32_32x32x16_bf16(a, b, c, 0, 0, 0);
}

// ---------------- convert x: f32 -> bf16, 4 elems/thread ----------------
__global__ void cvt_x_kernel(const float* __restrict__ x, ushort_t* __restrict__ xb, int n4) {
  int i = blockIdx.x * blockDim.x + threadIdx.x;
  if (i >= n4) return;
  float4 v = ((const float4*)x)[i];
  ushort4 o;
  o.x = f2b(v.x); o.y = f2b(v.y); o.z = f2b(v.z); o.w = f2b(v.w);
  ((ushort4*)xb)[i] = o;
}

// ------- convert + transpose W [512][512] f32 -> WT bf16, LDS-tiled -------
__global__ void cvt_wt_kernel(const float* __restrict__ W0, const float* __restrict__ W1,
                              const float* __restrict__ W2, const float* __restrict__ W3,
                              ushort_t* __restrict__ T0, ushort_t* __restrict__ T1,
                              ushort_t* __restrict__ T2, ushort_t* __restrict__ T3) {
  const float* W; ushort_t* T;
  switch (blockIdx.z) {
    case 0: W = W0; T = T0; break;
    case 1: W = W1; T = T1; break;
    case 2: W = W2; T = T2; break;
    default: W = W3; T = T3; break;
  }
  __shared__ ushort_t Tl[64 * 68];
  int t = threadIdx.x;
  int kt = blockIdx.x & 7, nt = blockIdx.x >> 3;
  int krow = t >> 4;
  int ncol = (t & 15) * 4;
#pragma unroll
  for (int j = 0; j < 4; ++j) {
    int k = j * 16 + krow;
    float4 v = *(const float4*)&W[(size_t)(kt * 64 + k) * 512 + nt * 64 + ncol];
    const float* vf = (const float*)&v;
#pragma unroll
    for (int e = 0; e < 4; ++e)
      Tl[(ncol + e) * 68 + k] = f2b(vf[e]);
  }
  __syncthreads();
#pragma unroll
  for (int j = 0; j < 4; ++j) {
    int f = j * 1024 + t * 4;
    int n = f >> 6, k = f & 63;
    *(ushort4*)&T[(size_t)(nt * 64 + n) * 512 + kt * 64 + k] =
        *(const ushort4*)&Tl[n * 68 + k];
  }
}

// ---------------- QKV projection GEMM, m97-style LDS-staged ----------------
__global__ __launch_bounds__(256) void gemm_qkv_kernel(
    const ushort_t* __restrict__ A,
    const ushort_t* __restrict__ WqT, const ushort_t* __restrict__ WkT,
    const ushort_t* __restrict__ WvT,
    ushort_t* __restrict__ Qo, ushort_t* __restrict__ Ko, ushort_t* __restrict__ VTo) {
  const int K = 512, N = 512, S = 4096;
  const ushort_t* BT; ushort_t* out; int mode;
  switch (blockIdx.z) {
    case 0: BT = WqT; out = Qo;  mode = 0; break;
    case 1: BT = WkT; out = Ko;  mode = 0; break;
    default: BT = WvT; out = VTo; mode = 1; break;
  }
  __shared__ ushort_t Al[128 * 64];
  __shared__ ushort_t Bl[128 * 64];

  int tid = threadIdx.x, lane = tid & 63, w = tid >> 6;
  int g = lane >> 4, ln = lane & 15;
  int wr = w >> 1, wc = w & 1;
  int m0 = blockIdx.y * 128;
  int n0 = blockIdx.x * 128;

  f32x4 acc[4][4];
  const f32x4 zz = {0.f, 0.f, 0.f, 0.f};
#pragma unroll
  for (int i = 0; i < 4; ++i)
#pragma unroll
    for (int j = 0; j < 4; ++j) acc[i][j] = zz;

  for (int kt = 0; kt < 8; ++kt) {
    __syncthreads();
#pragma unroll
    for (int i = 0; i < 4; ++i) {
      int p = i * 256 + tid, row = p >> 3, sl = p & 7, sp = sl ^ (row & 7);
      gld_lds16(A + (size_t)(m0 + row) * K + kt * 64 + sp * 8,
                (char*)Al + (i * 256 + (tid & 192)) * 16);
    }
#pragma unroll
    for (int i = 0; i < 4; ++i) {
      int p = i * 256 + tid, row = p >> 3, sl = p & 7, sp = sl ^ (row & 7);
      gld_lds16(BT + (size_t)(n0 + row) * K + kt * 64 + sp * 8,
                (char*)Bl + (i * 256 + (tid & 192)) * 16);
    }
    __syncthreads();

#pragma unroll
    for (int kc = 0; kc < 2; ++kc) {
      short8 af[4], bf[4];
#pragma unroll
      for (int mt = 0; mt < 4; ++mt) {
        int row = wr * 64 + mt * 16 + ln;
        af[mt] = *(const short8*)((char*)Al + row * 128 + (((kc * 4 + g) ^ (row & 7)) * 16));
      }
#pragma unroll
      for (int nt = 0; nt < 4; ++nt) {
        int row = wc * 64 + nt * 16 + ln;
        bf[nt] = *(const short8*)((char*)Bl + row * 128 + (((kc * 4 + g) ^ (row & 7)) * 16));
      }
#pragma unroll
      for (int mt = 0; mt < 4; ++mt)
#pragma unroll
        for (int nt = 0; nt < 4; ++nt)
          acc[mt][nt] = __builtin_amdgcn_mfma_f32_16x16x32_bf16(af[mt], bf[nt], acc[mt][nt], 0, 0, 0);
    }
  }

  if (mode == 0) {
#pragma unroll
    for (int mt = 0; mt < 4; ++mt)
#pragma unroll
      for (int nt = 0; nt < 4; ++nt)
#pragma unroll
        for (int jj = 0; jj < 4; ++jj) {
          int m = m0 + wr * 64 + mt * 16 + 4 * g + jj;
          int n = n0 + wc * 64 + nt * 16 + ln;
          out[(size_t)m * N + n] = f2b(acc[mt][nt][jj]);
        }
  } else {
#pragma unroll
    for (int mt = 0; mt < 4; ++mt)
#pragma unroll
      for (int nt = 0; nt < 4; ++nt) {
        int s0 = m0 + wr * 64 + mt * 16 + 4 * g;
        int u = n0 + wc * 64 + nt * 16 + ln;
        int b = s0 >> 12, s = s0 & 4095;
        int h = u >> 6, d = u & 63;
        us4 pv;
#pragma unroll
        for (int jj = 0; jj < 4; ++jj) pv[jj] = f2b(acc[mt][nt][jj]);
        *(us4*)&VTo[((size_t)((b * 8 + h) * 64 + d)) * S + s] = pv;
      }
  }
}

// ---------------- output projection GEMM: f32 out ----------------
__global__ __launch_bounds__(256) void gemm_ao_kernel(
    const ushort_t* __restrict__ A, const ushort_t* __restrict__ BT,
    float* __restrict__ out) {
  const int K = 512, N = 512;
  __shared__ ushort_t Al[128 * 64];
  __shared__ ushort_t Bl[128 * 64];

  int tid = threadIdx.x, lane = tid & 63, w = tid >> 6;
  int g = lane >> 4, ln = lane & 15;
  int wr = w >> 1, wc = w & 1;
  int m0 = blockIdx.y * 128;
  int n0 = blockIdx.x * 128;

  f32x4 acc[4][4];
  const f32x4 zz = {0.f, 0.f, 0.f, 0.f};
#pragma unroll
  for (int i = 0; i < 4; ++i)
#pragma unroll
    for (int j = 0; j < 4; ++j) acc[i][j] = zz;

  for (int kt = 0; kt < 8; ++kt) {
    __syncthreads();
#pragma unroll
    for (int i = 0; i < 4; ++i) {
      int p = i * 256 + tid, row = p >> 3, sl = p & 7, sp = sl ^ (row & 7);
      gld_lds16(A + (size_t)(m0 + row) * K + kt * 64 + sp * 8,
                (char*)Al + (i * 256 + (tid & 192)) * 16);
    }
#pragma unroll
    for (int i = 0; i < 4; ++i) {
      int p = i * 256 + tid, row = p >> 3, sl = p & 7, sp = sl ^ (row & 7);
      gld_lds16(BT + (size_t)(n0 + row) * K + kt * 64 + sp * 8,
                (char*)Bl + (i * 256 + (tid & 192)) * 16);
    }
    __syncthreads();

#pragma unroll
    for (int kc = 0; kc < 2; ++kc) {
      short8 af[4], bf[4];
#pragma unroll
      for (int mt = 0; mt < 4; ++mt) {
        int row = wr * 64 + mt * 16 + ln;
        af[mt] = *(const short8*)((char*)Al + row * 128 + (((kc * 4 + g) ^ (row & 7)) * 16));
      }
#pragma unroll
      for (int nt = 0; nt < 4; ++nt) {
        int row = wc * 64 + nt * 16 + ln;
        bf[nt] = *(const short8*)((char*)Bl + row * 128 + (((kc * 4 + g) ^ (row & 7)) * 16));
      }
#pragma unroll
      for (int mt = 0; mt < 4; ++mt)
#pragma unroll
        for (int nt = 0; nt < 4; ++nt)
          acc[mt][nt] = __builtin_amdgcn_mfma_f32_16x16x32_bf16(af[mt], bf[nt], acc[mt][nt], 0, 0, 0);
    }
  }
#pragma unroll
  for (int mt = 0; mt < 4; ++mt)
#pragma unroll
    for (int nt = 0; nt < 4; ++nt)
#pragma unroll
      for (int jj = 0; jj < 4; ++jj) {
        int m = m0 + wr * 64 + mt * 16 + 4 * g + jj;
        int n = n0 + wc * 64 + nt * 16 + ln;
        out[(size_t)m * N + n] = acc[mt][nt][jj];
      }
}

// ---------------- flash attention: 8-wave, 32 q/wave, 32x32 MFMA ----------------
// grid (S/256, H, 2*nparts); 512 threads. Wave w owns q [qb*256+w*32, +32).
// Swapped QK^T (A=K from LDS, B=Q in regs); PV B-frag = P in native C/D order
// (4 cvtpk, no cross-lane); V staged QUAD-PERMUTED (middle quads swapped per
// 16-group) so a contiguous b128 read yields m_A == m_B (operand-invariance).
__global__ __launch_bounds__(512, 4) void attn_kernel(
    const ushort_t* __restrict__ Qg, const ushort_t* __restrict__ Kg,
    const ushort_t* __restrict__ VTg, ushort_t* __restrict__ Obuf,
    float* __restrict__ Lbuf, int ntiles) {
  const int S = 4096, U = 512;
  const float CSC = 0.125f * 1.44269504089f;   // scale * log2(e)
  int qb = blockIdx.x, h = blockIdx.y;
  int b = blockIdx.z & 1, part = blockIdx.z >> 1;
  int bh = b * 8 + h;
  int tid = threadIdx.x, lane = tid & 63, w = tid >> 6;
  int lq = lane & 31, hi = lane >> 5;
  int lx = (lq & 7) << 4;              // row-XOR term (same for lq and 32+lq)

  __shared__ ushort_t Kl[64 * 64];     // [kv][d]  8 KB, XOR-swizzled rows
  __shared__ ushort_t Vl[64 * 64];     // [d][kv]  8 KB, swizzled + quad-permuted

  // Q B-frags: contiguous 8 elems, matching K A-frag contiguous load
  int qrow = qb * 256 + w * 32 + lq;
  const ushort_t* qp = Qg + ((size_t)b * S + qrow) * U + h * 64 + hi * 8;
  short8 qf[4];
#pragma unroll
  for (int s = 0; s < 4; ++s) qf[s] = *(const short8*)(qp + 16 * s);

  f32x16 acc0 = {}, acc1 = {};         // ctx^T: col=q=lq, rows d (2 d-tiles)
  float mrun = -INFINITY, lrun = 0.f;

  // staging: 512 threads, 1 uint4 each for K and V
  int r = tid >> 3, c8 = (tid & 7) * 8;
  int wby = (r * 128 + c8 * 2) ^ ((r & 7) << 4);     // K: linear row layout
  // V: quad-permute within 16-group: quads {0,1,2,3} stored at pos {0,2,1,3}
  int vg16 = (c8 >> 4) * 32;           // byte base of 16-kv group (4 quads x 8B)
  int vpi  = (c8 >> 3) & 1;            // which quad pair this thread holds
  int vb0 = r * 128 + ((vg16 + vpi * 8) ^ ((r & 7) << 4));        // pos 4g+pi
  int vb1 = r * 128 + ((vg16 + vpi * 8 + 16) ^ ((r & 7) << 4));   // pos 4g+pi+2
  int it0 = part * ntiles;
  const ushort_t* kp = Kg + ((size_t)b * S + it0 * 64 + r) * U + h * 64 + c8;
  const ushort_t* vp = VTg + ((size_t)(bh * 64 + r)) * S + it0 * 64 + c8;

  uint4 kst = *(const uint4*)kp;       // prefetch tile 0
  uint4 vst = *(const uint4*)vp;

#define KREAD(rowv, colb) \
  (*(const short8*)((char*)Kl + ((((rowv) * 128) + (colb)) ^ lx)))

  // V^T A-frag, k-step t: contiguous b128; permuted layout makes slots j=0..3
  // <- kv 16t+4hi+(0..3), j=4..7 <- kv 16t+8+4hi+(0..3) == P's C/D distribution
#define VREADP(rowv, t) \
  (*(const short8*)((char*)Vl + ((((rowv) * 128) + 32 * (t) + 16 * hi) ^ lx)))

  // P B-frag: native C/D order, no cross-lane exchange
#define MKPF(stv, ks, pfout)                                      \
  {                                                               \
    union { uint_t u[4]; short8 s; } pu;                          \
    pu.u[0] = cvtpk(stv[8 * ks + 0], stv[8 * ks + 1]);            \
    pu.u[1] = cvtpk(stv[8 * ks + 2], stv[8 * ks + 3]);            \
    pu.u[2] = cvtpk(stv[8 * ks + 4], stv[8 * ks + 5]);            \
    pu.u[3] = cvtpk(stv[8 * ks + 6], stv[8 * ks + 7]);            \
    pfout = pu.s;                                                 \
  }

  for (int ii = 0; ii < ntiles; ++ii) {
    __syncthreads();                   // prev tile fully consumed
    *(uint4*)((char*)Kl + wby) = kst;
    {
      uint2 q0; q0.x = vst.x; q0.y = vst.y;
      uint2 q1; q1.x = vst.z; q1.y = vst.w;
      *(uint2*)((char*)Vl + vb0) = q0;
      *(uint2*)((char*)Vl + vb1) = q1;
    }
    __syncthreads();                   // tile staged
    if (ii + 1 < ntiles) {             // T14: next loads drain under compute
      kp += (size_t)64 * U;
      vp += 64;
      kst = *(const uint4*)kp;
      vst = *(const uint4*)vp;
    }

    // ---- S^T = K . Q^T : rows=kv (2 chunks of 32), cols=q ----
    f32x16 st0 = {}, st1 = {};
#pragma unroll
    for (int s = 0; s < 4; ++s)
      st0 = mfma32(KREAD(lq, 32 * s + 16 * hi), qf[s], st0);
#pragma unroll
    for (int s = 0; s < 4; ++s)
      st1 = mfma32(KREAD(32 + lq, 32 * s + 16 * hi), qf[s], st1);

    // ---- softmax (exp2 domain): in-register max tree + shfl_xor(32) ----
    float a0 = max3f(st0[0], st0[1], st0[2]);
    float a1 = max3f(st0[3], st0[4], st0[5]);
    float a2 = max3f(st0[6], st0[7], st0[8]);
    float a3 = max3f(st0[9], st0[10], st0[11]);
    float a4 = max3f(st0[12], st0[13], st0[14]);
    float a5 = max3f(st0[15], st1[0], st1[1]);
    float a6 = max3f(st1[2], st1[3], st1[4]);
    float a7 = max3f(st1[5], st1[6], st1[7]);
    float a8 = max3f(st1[8], st1[9], st1[10]);
    float a9 = max3f(st1[11], st1[12], st1[13]);
    float aa = fmaxf(st1[14], st1[15]);
    float smax = fmaxf(fmaxf(max3f(a0, a1, a2), max3f(a3, a4, a5)),
                       fmaxf(max3f(a6, a7, a8), fmaxf(a9, aa)));
    float tmax = fmaxf(smax, __shfl_xor(smax, 32)) * CSC;

    float mnew = fmaxf(mrun, tmax);
    if (!__all(tmax <= mrun + 8.0f)) {   // T13 defer-max
      float alpha = __builtin_amdgcn_exp2f(mrun - mnew);
      mrun = mnew;
      lrun *= alpha;
#pragma unroll
      for (int i = 0; i < 16; ++i) { acc0[i] *= alpha; acc1[i] *= alpha; }
    }

    float nb = -mrun;
    float ps = 0.f;
#pragma unroll
    for (int i = 0; i < 16; ++i) {
      float y0 = __builtin_amdgcn_exp2f(__builtin_fmaf(st0[i], CSC, nb));
      float y1 = __builtin_amdgcn_exp2f(__builtin_fmaf(st1[i], CSC, nb));
      st0[i] = y0; st1[i] = y1;
      ps += y0 + y1;
    }
    ps += __shfl_xor(ps, 32);
    lrun += ps;

    // ---- PV: ctx^T += V^T-frag . P-frag (m_A == m_B by construction) ----
    short8 pf;
    MKPF(st0, 0, pf);
    acc0 = mfma32(VREADP(lq, 0), pf, acc0);
    acc1 = mfma32(VREADP(32 + lq, 0), pf, acc1);
    MKPF(st0, 1, pf);
    acc0 = mfma32(VREADP(lq, 1), pf, acc0);
    acc1 = mfma32(VREADP(32 + lq, 1), pf, acc1);
    MKPF(st1, 0, pf);
    acc0 = mfma32(VREADP(lq, 2), pf, acc0);
    acc1 = mfma32(VREADP(32 + lq, 2), pf, acc1);
    MKPF(st1, 1, pf);
    acc0 = mfma32(VREADP(lq, 3), pf, acc0);
    acc1 = mfma32(VREADP(32 + lq, 3), pf, acc1);
  }

  // ---- store normalized partial (ctx^T rows d -> Obuf[s][d]) + log2 weight ----
  float inv = 1.f / lrun;
  ushort_t* ob = Obuf + (size_t)part * 4194304 +
                 ((size_t)bh * S + qb * 256 + w * 32 + lq) * 64;
#pragma unroll
  for (int g4 = 0; g4 < 4; ++g4) {     // d = 8*g4 + 4*hi + (0..3)
    uint2 o;
    o.x = cvtpk(acc0[4 * g4 + 0] * inv, acc0[4 * g4 + 1] * inv);
    o.y = cvtpk(acc0[4 * g4 + 2] * inv, acc0[4 * g4 + 3] * inv);
    *(uint2*)(ob + 8 * g4 + 4 * hi) = o;
  }
#pragma unroll
  for (int g4 = 0; g4 < 4; ++g4) {     // d = 32 + 8*g4 + 4*hi + (0..3)
    uint2 o;
    o.x = cvtpk(acc1[4 * g4 + 0] * inv, acc1[4 * g4 + 1] * inv);
    o.y = cvtpk(acc1[4 * g4 + 2] * inv, acc1[4 * g4 + 3] * inv);
    *(uint2*)(ob + 32 + 8 * g4 + 4 * hi) = o;
  }
  if (hi == 0)
    Lbuf[part * 65536 + bh * S + qb * 256 + w * 32 + lq] = mrun + __log2f(lrun);
#undef KREAD
#undef VREADP
#undef MKPF
}

// ---------------- combine partials -> CTX bf16 natural layout ----------------
__global__ void combine_kernel(const ushort_t* __restrict__ Obuf,
                               const float* __restrict__ Lbuf,
                               ushort_t* __restrict__ CTX, int nparts) {
  int tid = threadIdx.x;
  int row = blockIdx.x * 32 + (tid >> 3);   // bh*4096 + s
  int c = (tid & 7) * 8;
  int bh = row >> 12, s = row & 4095;
  int b = bh >> 3, h = bh & 7;

  float o[8];
#pragma unroll
  for (int j = 0; j < 8; ++j) o[j] = 0.f;

  if (nparts == 1) {
    us4 n0a = *(const us4*)&Obuf[(size_t)row * 64 + c];
    us4 n0b = *(const us4*)&Obuf[(size_t)row * 64 + c + 4];
#pragma unroll
    for (int j = 0; j < 4; ++j) { o[j] = b2f(n0a[j]); o[j + 4] = b2f(n0b[j]); }
  } else {
    float Lm = -INFINITY;
    for (int p = 0; p < nparts; ++p) Lm = fmaxf(Lm, Lbuf[p * 65536 + row]);
    float wsum = 0.f;
    for (int p = 0; p < nparts; ++p) {
      float wp = __builtin_amdgcn_exp2f(Lbuf[p * 65536 + row] - Lm);
      wsum += wp;
      const ushort_t* op = &Obuf[(size_t)p * 4194304 + (size_t)row * 64 + c];
      us4 na = *(const us4*)op;
      us4 nb2 = *(const us4*)(op + 4);
#pragma unroll
      for (int j = 0; j < 4; ++j) {
        o[j]     += wp * b2f(na[j]);
        o[j + 4] += wp * b2f(nb2[j]);
      }
    }
    float inv = 1.f / wsum;
#pragma unroll
    for (int j = 0; j < 8; ++j) o[j] *= inv;
  }

  us4 w0v, w1v;
#pragma unroll
  for (int j = 0; j < 4; ++j) { w0v[j] = f2b(o[j]); w1v[j] = f2b(o[j + 4]); }
  ushort_t* dst = &CTX[((size_t)(b * 4096 + s)) * 512 + h * 64 + c];
  *(us4*)dst = w0v;
  *(us4*)(dst + 4) = w1v;
}

extern "C" void kernel_launch(void* const* d_in, const int* in_sizes, int n_in,
                              void* d_out, int out_size, void* d_ws, size_t ws_size,
                              hipStream_t stream) {
  const float* x  = (const float*)d_in[0];
  const float* Wq = (const float*)d_in[1];
  const float* Wk = (const float*)d_in[2];
  const float* Wv = (const float*)d_in[3];
  const float* Wo = (const float*)d_in[4];
  float* out = (float*)d_out;

  ushort_t* ws  = (ushort_t*)d_ws;
  ushort_t* xb  = ws;                 // 8MB (reused for CTX after gemm_qkv)
  ushort_t* WqT = xb + 4194304;
  ushort_t* WkT = WqT + 262144;
  ushort_t* WvT = WkT + 262144;
  ushort_t* WoT = WvT + 262144;
  ushort_t* Qb  = WoT + 262144;
  ushort_t* Kb  = Qb + 4194304;
  ushort_t* VTb = Kb + 4194304;
  ushort_t* Obuf = VTb + 4194304;     // nparts * 8MB
  ushort_t* CTX = xb;

  // bytes needed: 2*(4194304 + 1048576 + 12582912 + nparts*4194304) + nparts*262144
  int nparts = (ws_size >= 70254592u) ? 4 : ((ws_size >= 52953088u) ? 2 : 1);
  float* Lbuf = (float*)(Obuf + (size_t)nparts * 4194304);
  int ntiles = 64 / nparts;

  cvt_x_kernel<<<4096, 256, 0, stream>>>(x, xb, 1048576);
  cvt_wt_kernel<<<dim3(64, 1, 4), 256, 0, stream>>>(Wq, Wk, Wv, Wo, WqT, WkT, WvT, WoT);
  gemm_qkv_kernel<<<dim3(4, 64, 3), 256, 0, stream>>>(xb, WqT, WkT, WvT, Qb, Kb, VTb);
  attn_kernel<<<dim3(16, 8, 2 * nparts), 512, 0, stream>>>(Qb, Kb, VTb, Obuf, Lbuf, ntiles);
  combine_kernel<<<2048, 256, 0, stream>>>(Obuf, Lbuf, CTX, nparts);
  gemm_ao_kernel<<<dim3(4, 64), 256, 0, stream>>>(CTX, WoT, out);
}